// Round 9
// baseline (306.155 us; speedup 1.0000x reference)
//
#include <hip/hip_runtime.h>

using u16 = unsigned short;
using u32 = unsigned int;
typedef __attribute__((ext_vector_type(8))) short short8;
typedef __attribute__((ext_vector_type(4))) float f32x4;

#define LOG2E 1.4426950408889634f
#define SCALE2 0.18033688011112042f  // 0.125 * log2(e)

__device__ __forceinline__ u16 f2b(float f) {  // RNE fp32->bf16
  union { float f; unsigned u; } v; v.f = f;
  unsigned r = v.u + 0x7fffu + ((v.u >> 16) & 1u);
  return (u16)(r >> 16);
}

// Raw workgroup barrier: seals LDS ops (lgkmcnt 0) without forcing vmcnt drain.
__device__ __forceinline__ void wg_barrier() {
  asm volatile("s_waitcnt lgkmcnt(0)\n\ts_barrier" ::: "memory");
}

// Direct global->LDS DMA, 16B per lane.
__device__ __forceinline__ void gload_lds16(const void* g, void* l) {
  __builtin_amdgcn_global_load_lds(
      (const __attribute__((address_space(1))) unsigned int*)g,
      (__attribute__((address_space(3))) unsigned int*)l, 16, 0, 0);
}

// ---------------- merged prep: weight pack | rope table | layernorm ----------------
// (mask prepack removed: attention reads the fp32 mask directly)
__global__ __launch_bounds__(256) void prep(const float* __restrict__ w_qkv, u16* __restrict__ wqkv_b,
                                            const float* __restrict__ in_w, u16* __restrict__ inw_b,
                                            const float* __restrict__ out_w, u16* __restrict__ outw_b,
                                            float2* __restrict__ rtab,
                                            const float* __restrict__ x,
                                            const float* __restrict__ ln_g,
                                            const float* __restrict__ ln_b,
                                            u16* __restrict__ xn) {
  __shared__ float sbuf[4], ssbuf[4];
  int blk = blockIdx.x, t = threadIdx.x;
  if (blk < 7168) {            // ---- fp32 -> bf16 weight pack
    int i = blk * 256 + t;
    const float* s; u16* d; int off;
    if (i < 786432)       { s = w_qkv; d = wqkv_b; off = i; }
    else if (i < 1572864) { s = in_w;  d = inw_b;  off = i - 786432; }
    else                  { s = out_w; d = outw_b; off = i - 1572864; }
    float4 v = ((const float4*)s)[off];
    uint2 o;
    o.x = (unsigned)f2b(v.x) | ((unsigned)f2b(v.y) << 16);
    o.y = (unsigned)f2b(v.z) | ((unsigned)f2b(v.w) << 16);
    ((uint2*)d)[off] = o;
  } else if (blk < 11264) {    // ---- RoPE cos/sin table
    int idx = (blk - 7168) * 256 + t;   // 1048576
    int pos = idx >> 9, i = idx & 511;
    float ifreq = exp2f(-(float)(2 * i) * (13.287712379549449f / 1024.0f));
    float ang = (float)pos * ifreq;
    rtab[idx] = make_float2(__cosf(ang), __sinf(ang));
  } else {                     // ---- LayerNorm rows 0..4095 -> bf16
    int row = blk - 11264;
    const float* xr = x + (size_t)row * 1024;
    float4 v = *(const float4*)(xr + t * 4);
    float s = v.x + v.y + v.z + v.w;
    float ss = v.x * v.x + v.y * v.y + v.z * v.z + v.w * v.w;
    #pragma unroll
    for (int m = 1; m < 64; m <<= 1) {
      s  += __shfl_xor(s, m);
      ss += __shfl_xor(ss, m);
    }
    int wave = t >> 6, lane = t & 63;
    if (lane == 0) { sbuf[wave] = s; ssbuf[wave] = ss; }
    __syncthreads();
    s  = sbuf[0] + sbuf[1] + sbuf[2] + sbuf[3];
    ss = ssbuf[0] + ssbuf[1] + ssbuf[2] + ssbuf[3];
    float mean = s * (1.0f / 1024.0f);
    float var  = ss * (1.0f / 1024.0f) - mean * mean;
    float rstd = 1.0f / sqrtf(var + 1e-5f);
    float4 gv = *(const float4*)(ln_g + t * 4);
    float4 bv = *(const float4*)(ln_b + t * 4);
    uint2 o;
    o.x = (unsigned)f2b((v.x - mean) * rstd * gv.x + bv.x) |
          ((unsigned)f2b((v.y - mean) * rstd * gv.y + bv.y) << 16);
    o.y = (unsigned)f2b((v.z - mean) * rstd * gv.z + bv.z) |
          ((unsigned)f2b((v.w - mean) * rstd * gv.w + bv.w) << 16);
    *(uint2*)(xn + (size_t)row * 1024 + t * 4) = o;
  }
}

// ======== GEMM: BK=32, 3-buffer distance-2 pipeline, global_load_lds DMA
// staging, counted vmcnt(4) at barriers. Linear [128][32] LDS tiles with chunk
// swizzle (both-sides involution). K=1024 assumed (32 tiles). ========
template<bool SLAB, bool OUT_BF16, bool ROPE, bool WVT>
__global__ __launch_bounds__(256, 3) void gemm_pipe(const u16* __restrict__ A, int lda,
                                                    const u16* __restrict__ W,
                                                    const float* __restrict__ bias,
                                                    const float2* __restrict__ rtab,
                                                    float* __restrict__ Cf,
                                                    u16* __restrict__ Cb,
                                                    u16* __restrict__ vT,
                                                    int ldc, int K) {
  __shared__ u16 As[3][128 * 32];
  __shared__ u16 Bs[3][128 * 32];
  int n0 = blockIdx.x * 128, m0 = blockIdx.y * 128;
  int aoff = SLAB ? ((n0 >> 10) << 10) : 0;
  int tid = threadIdx.x;
  int lane = tid & 63, l15 = lane & 15, quad = lane >> 4;
  int w = tid >> 6, mw = w & 1, nw = w >> 1;
  const u16* Abase = A + (size_t)m0 * lda + aoff;
  const u16* Wbase = W + (size_t)n0 * K;
  f32x4 acc[4][4];
  #pragma unroll
  for (int i = 0; i < 4; i++)
    #pragma unroll
    for (int j = 0; j < 4; j++) acc[i][j] = (f32x4){0.f, 0.f, 0.f, 0.f};

  // per-lane DMA source pointers (chunk-swizzled); advance +64B per tile
  int rl = lane >> 2;
  int qs = ((lane & 3) ^ ((lane >> 3) & 3)) * 16;   // byte offset of 16B chunk
  const char* gA0 = (const char*)(Abase + (size_t)(w * 16 + rl) * lda) + qs;
  const char* gA1 = (const char*)(Abase + (size_t)((w + 4) * 16 + rl) * lda) + qs;
  const char* gB0 = (const char*)(Wbase + (size_t)(w * 16 + rl) * K) + qs;
  const char* gB1 = (const char*)(Wbase + (size_t)((w + 4) * 16 + rl) * K) + qs;
  int p16 = (quad ^ ((l15 >> 1) & 3)) * 8;          // u16 offset of swizzled chunk

  #define ISSUE(bf)                                                           \
    gload_lds16(gA0, &As[bf][(w) * 512]);                                     \
    gload_lds16(gA1, &As[bf][(w + 4) * 512]);                                 \
    gload_lds16(gB0, &Bs[bf][(w) * 512]);                                     \
    gload_lds16(gB1, &Bs[bf][(w + 4) * 512]);                                 \
    gA0 += 64; gA1 += 64; gB0 += 64; gB1 += 64;
  #define WBAR4() asm volatile("s_waitcnt vmcnt(4) lgkmcnt(0)\n\ts_barrier" ::: "memory")
  #define WBAR0() asm volatile("s_waitcnt vmcnt(0) lgkmcnt(0)\n\ts_barrier" ::: "memory")
  #define COMPUTE(bf)                                                         \
    {                                                                         \
      short8 af[4], bfr[4];                                                   \
      _Pragma("unroll")                                                       \
      for (int mt = 0; mt < 4; mt++)                                          \
        af[mt] = *(const short8*)&As[bf][(mw * 64 + mt * 16 + l15) * 32 + p16]; \
      _Pragma("unroll")                                                       \
      for (int nt = 0; nt < 4; nt++)                                          \
        bfr[nt] = *(const short8*)&Bs[bf][(nw * 64 + nt * 16 + l15) * 32 + p16]; \
      _Pragma("unroll")                                                       \
      for (int mt = 0; mt < 4; mt++)                                          \
        _Pragma("unroll")                                                     \
        for (int nt = 0; nt < 4; nt++)                                        \
          acc[mt][nt] = __builtin_amdgcn_mfma_f32_16x16x32_bf16(              \
              af[mt], bfr[nt], acc[mt][nt], 0, 0, 0);                         \
    }

  ISSUE(0);            // tile 0
  ISSUE(1);            // tile 1
  WBAR4();             // tile 0 resident
  #pragma unroll 1
  for (int tt = 0; tt < 10; ++tt) {
    ISSUE(2); COMPUTE(0); WBAR4();
    ISSUE(0); COMPUTE(1); WBAR4();
    ISSUE(1); COMPUTE(2); WBAR4();
  }
  COMPUTE(0); WBAR0(); // tile 30; drain tile 31
  COMPUTE(1);          // tile 31
  #undef ISSUE
  #undef WBAR4
  #undef WBAR0
  #undef COMPUTE

  int mb = m0 + mw * 64, nb = n0 + nw * 64;
  float bv[4];
  #pragma unroll
  for (int nt = 0; nt < 4; nt++) bv[nt] = bias[nb + nt * 16 + l15];
  #pragma unroll
  for (int mt = 0; mt < 4; mt++)
    #pragma unroll
    for (int nt = 0; nt < 4; nt++) {
      int col = nb + nt * 16 + l15;
      if (WVT && col >= 2048) {
        // v-columns: write transposed to vT[bb][h][d][s] (4 consecutive s per lane)
        int hh = (col - 2048) >> 6, dd = (col - 2048) & 63;
        int row0 = mb + mt * 16 + quad * 4;
        int bbi = row0 >> 11, s0 = row0 & 2047;
        u16 vv[4];
        #pragma unroll
        for (int reg = 0; reg < 4; reg++) vv[reg] = f2b(acc[mt][nt][reg] + bv[nt]);
        *(uint2*)&vT[((size_t)((bbi * 16 + hh) * 64 + dd)) * 2048 + s0] = *(uint2*)vv;
      } else {
        #pragma unroll
        for (int reg = 0; reg < 4; reg++) {
          int row = mb + mt * 16 + quad * 4 + reg;   // C/D: row=quad*4+reg, col=l15
          float val = acc[mt][nt][reg] + bv[nt];
          if (ROPE && col < 2048) {
            float pr = __shfl_xor(val, 1);
            float2 cs = rtab[(size_t)(row & 2047) * 512 + ((col & 1023) >> 1)];
            val = (col & 1) ? fmaf(val, cs.x, pr * cs.y)
                            : fmaf(val, cs.x, -pr * cs.y);
          }
          if (OUT_BF16) Cb[(size_t)row * ldc + col] = f2b(val);
          else          Cf[(size_t)row * ldc + col] = val;
        }
      }
    }
}

// ---------------- Flash attention: MQ=128, 8 waves = 4 q-groups x 2 k-halves ----------------
// Round-2 verified structure (best measured attn: 56.3us), with ONE change:
// mask read directly as fp32 from the original [b][q][k] layout (the maskp
// prepack is deleted). Per (p,mt) a float4 at mask[(qrow)*2048 + k]; quads
// cover 64B contiguous; LOG2E applied at use (fp32, more accurate than the
// old bf16-rounded prepack). Prefetched one kt ahead like before.
__global__ __launch_bounds__(512, 4) void attn_mfma(const u16* __restrict__ qkv2,
                                                    const u16* __restrict__ vT,
                                                    const float* __restrict__ mask,
                                                    u16* __restrict__ attn_out) {
  __shared__ u16 Kb[2][64 * 72];
  __shared__ u16 Vb[2][64 * 72];
  __shared__ u16 Ps[128 * 72];
  __shared__ float lsf[128];     // [wq][p][l15] row-sum partials from wk=1 waves
  int h = blockIdx.x, qt = blockIdx.y, bb = blockIdx.z;
  int tid = threadIdx.x;
  int lane = tid & 63, l15 = lane & 15, quad = lane >> 4;
  int w = tid >> 6;
  int wq = w & 3, wk = w >> 2;             // q-group 0..3, k-half 0..1
  int sr = tid >> 3, sc = (tid & 7) * 8;   // K/V staging: 1 uint4 per thread (64x64 tile)
  const u16* kslab = qkv2 + ((size_t)bb * 2048) * 3072 + 1024 + h * 64;
  const u16* vslab = vT + ((size_t)((bb * 16 + h) * 64)) * 2048;

  {  // stage Q rows 0..127 (all waves cooperate; barrier below before bq reads)
    int r = tid >> 2, c0 = (tid & 3) * 16;
    const u16* src = qkv2 + (size_t)(bb * 2048 + qt * 128 + r) * 3072 + h * 64 + c0;
    *(uint4*)&Ps[r * 72 + c0]     = *(const uint4*)src;
    *(uint4*)&Ps[r * 72 + c0 + 8] = *(const uint4*)(src + 8);
  }
  {  // stage K/V tile 0
    *(uint4*)&Kb[0][sr * 72 + sc] = *(const uint4*)(kslab + (size_t)sr * 3072 + sc);
    *(uint4*)&Vb[0][sr * 72 + sc] = *(const uint4*)(vslab + (size_t)sr * 2048 + sc);
  }
  // fp32 mask base for this lane: row = bb*2048 + qt*128 + wq*32 + p*16 + l15,
  // col = kt*64 + wk*32 + mt*16 + quad*4. p stride = 16*2048; mt stride = 16.
  const float* mptr = mask + (size_t)(bb * 2048 + qt * 128 + wq * 32 + l15) * 2048
                      + wk * 32 + quad * 4;
  float4 mc[2][2];
  #pragma unroll
  for (int p = 0; p < 2; p++)
    #pragma unroll
    for (int mt = 0; mt < 2; mt++)
      mc[p][mt] = *(const float4*)(mptr + p * 32768 + mt * 16);
  wg_barrier();

  short8 bq[2][2];
  #pragma unroll
  for (int p = 0; p < 2; p++)
    #pragma unroll
    for (int hk = 0; hk < 2; hk++)
      bq[p][hk] = *(const short8*)&Ps[(wq * 32 + p * 16 + l15) * 72 + hk * 32 + quad * 8];
  float lsum[2] = {0.f, 0.f};
  f32x4 acc[2][4];
  #pragma unroll
  for (int p = 0; p < 2; p++)
    #pragma unroll
    for (int dt = 0; dt < 4; dt++) acc[p][dt] = (f32x4){0.f, 0.f, 0.f, 0.f};

  for (int kt = 0; kt < 32; kt++) {
    int b = kt & 1;
    uint4 kr, vr;
    float4 mn[2][2];
    if (kt + 1 < 32) {  // prefetch next K/V tile and next mask fragments
      kr = *(const uint4*)(kslab + (size_t)((kt + 1) * 64 + sr) * 3072 + sc);
      vr = *(const uint4*)(vslab + (size_t)sr * 2048 + (kt + 1) * 64 + sc);
      #pragma unroll
      for (int p = 0; p < 2; p++)
        #pragma unroll
        for (int mt = 0; mt < 2; mt++)
          mn[p][mt] = *(const float4*)(mptr + (kt + 1) * 64 + p * 32768 + mt * 16);
    }
    short8 ak[2][2];
    #pragma unroll
    for (int mt = 0; mt < 2; mt++)
      #pragma unroll
      for (int hk = 0; hk < 2; hk++)
        ak[mt][hk] = *(const short8*)&Kb[b][(wk * 32 + mt * 16 + l15) * 72 + hk * 32 + quad * 8];
    f32x4 st[2][2];
    #pragma unroll
    for (int p = 0; p < 2; p++)
      #pragma unroll
      for (int mt = 0; mt < 2; mt++) {
        f32x4 z = (f32x4){0.f, 0.f, 0.f, 0.f};
        z = __builtin_amdgcn_mfma_f32_16x16x32_bf16(ak[mt][0], bq[p][0], z, 0, 0, 0);
        st[p][mt] = __builtin_amdgcn_mfma_f32_16x16x32_bf16(ak[mt][1], bq[p][1], z, 0, 0, 0);
      }
    #pragma unroll
    for (int p = 0; p < 2; p++) {
      int prow = (wq * 32 + p * 16 + l15) * 72 + wk * 32 + quad * 4;
      #pragma unroll
      for (int mt = 0; mt < 2; mt++) {
        float sv0 = fmaf(st[p][mt][0], SCALE2, mc[p][mt].x * LOG2E);
        float sv1 = fmaf(st[p][mt][1], SCALE2, mc[p][mt].y * LOG2E);
        float sv2 = fmaf(st[p][mt][2], SCALE2, mc[p][mt].z * LOG2E);
        float sv3 = fmaf(st[p][mt][3], SCALE2, mc[p][mt].w * LOG2E);
        float p0 = __builtin_amdgcn_exp2f(sv0), p1 = __builtin_amdgcn_exp2f(sv1);
        float p2 = __builtin_amdgcn_exp2f(sv2), p3 = __builtin_amdgcn_exp2f(sv3);
        lsum[p] += (p0 + p1) + (p2 + p3);
        u32 pk0, pk1;
        asm("v_cvt_pk_bf16_f32 %0, %1, %2" : "=v"(pk0) : "v"(p0), "v"(p1));
        asm("v_cvt_pk_bf16_f32 %0, %1, %2" : "=v"(pk1) : "v"(p2), "v"(p3));
        *(uint2*)&Ps[prow + mt * 16] = make_uint2(pk0, pk1);
      }
    }
    short8 ap[2];
    #pragma unroll
    for (int p = 0; p < 2; p++)
      ap[p] = *(const short8*)&Ps[(wq * 32 + p * 16 + l15) * 72 + wk * 32 + quad * 8];
    #pragma unroll
    for (int dt = 0; dt < 4; dt++) {
      short8 bv = *(const short8*)&Vb[b][(dt * 16 + l15) * 72 + wk * 32 + quad * 8];
      #pragma unroll
      for (int p = 0; p < 2; p++)
        acc[p][dt] = __builtin_amdgcn_mfma_f32_16x16x32_bf16(ap[p], bv, acc[p][dt], 0, 0, 0);
    }
    if (kt + 1 < 32) {
      int nb = b ^ 1;
      *(uint4*)&Kb[nb][sr * 72 + sc] = kr;
      *(uint4*)&Vb[nb][sr * 72 + sc] = vr;
      #pragma unroll
      for (int p = 0; p < 2; p++)
        #pragma unroll
        for (int mt = 0; mt < 2; mt++)
          mc[p][mt] = mn[p][mt];
    }
    wg_barrier();
  }

  // ---- cross-k-wave combine: wk=1 dumps O-partials + row sums; wk=0 merges ----
  float* fs = ((wq < 2) ? (float*)&Kb[0][0] : (float*)&Vb[0][0]) + (wq & 1) * 2176;
  if (wk) {
    #pragma unroll
    for (int p = 0; p < 2; p++) {
      #pragma unroll
      for (int dt = 0; dt < 4; dt++)
        #pragma unroll
        for (int reg = 0; reg < 4; reg++)
          fs[(p * 16 + quad * 4 + reg) * 68 + dt * 16 + l15] = acc[p][dt][reg];
      float l = lsum[p];
      l += __shfl_xor(l, 16);
      l += __shfl_xor(l, 32);
      if (lane < 16) lsf[(wq * 2 + p) * 16 + l15] = l;
    }
  }
  wg_barrier();
  if (!wk) {
    #pragma unroll
    for (int p = 0; p < 2; p++) {
      float l = lsum[p];
      l += __shfl_xor(l, 16);
      l += __shfl_xor(l, 32);
      l += lsf[(wq * 2 + p) * 16 + l15];     // full row sum for q = l15 (local)
      #pragma unroll
      for (int reg = 0; reg < 4; reg++) {
        float lq = __shfl(l, quad * 4 + reg);
        float inv = 1.0f / lq;
        int grow = bb * 2048 + qt * 128 + wq * 32 + p * 16 + quad * 4 + reg;
        #pragma unroll
        for (int dt = 0; dt < 4; dt++) {
          float o = acc[p][dt][reg] + fs[(p * 16 + quad * 4 + reg) * 68 + dt * 16 + l15];
          attn_out[(size_t)grow * 1024 + h * 64 + dt * 16 + l15] = f2b(o * inv);
        }
      }
    }
  }
}

extern "C" void kernel_launch(void* const* d_in, const int* in_sizes, int n_in,
                              void* d_out, int out_size, void* d_ws, size_t ws_size,
                              hipStream_t stream) {
  const float* x     = (const float*)d_in[0];
  const float* mask  = (const float*)d_in[1];
  const float* ln_g  = (const float*)d_in[2];
  const float* ln_b  = (const float*)d_in[3];
  const float* w_qkv = (const float*)d_in[4];
  const float* b_qkv = (const float*)d_in[5];
  const float* in_w  = (const float*)d_in[6];
  const float* in_b  = (const float*)d_in[7];
  const float* out_w = (const float*)d_in[8];
  const float* out_b = (const float*)d_in[9];
  float* out = (float*)d_out;
  char* ws = (char*)d_ws;

  u16* wqkv_b = (u16*)(ws);                   //  6291456  (3072x1024)
  u16* inw_b  = (u16*)(ws + 6291456ull);      //  6291456  (3072x1024)
  u16* outw_b = (u16*)(ws + 12582912ull);     //  2097152  (1024x1024)
  u16* xn_b   = (u16*)(ws + 14680064ull);     //  8388608  (4096x1024)
  u16* attn_b = xn_b;                         //  reuse (xn dead after gemm1)
  u16* qkv_b  = (u16*)(ws + 23068672ull);     // 25165824  (4096x3072)
  u16* qkv2_b = (u16*)(ws + 48234496ull);     // 25165824  (4096x3072; v cols unused)
  float2* rtab = (float2*)qkv2_b;             //  8388608  aliases qkv2 (dead before gemm2)
  u16* vT     = (u16*)(ws + 73400320ull);     //  8388608  (2,16,64,2048)

  prep<<<15360, 256, 0, stream>>>(w_qkv, wqkv_b, in_w, inw_b, out_w, outw_b,
                                  rtab, x, ln_g, ln_b, xn_b);
  gemm_pipe<false, true, true, false><<<dim3(24, 32), 256, 0, stream>>>(
      xn_b, 1024, wqkv_b, b_qkv, rtab, nullptr, qkv_b, nullptr, 3072, 1024);
  gemm_pipe<true, true, false, true><<<dim3(24, 32), 256, 0, stream>>>(
      qkv_b, 3072, inw_b, in_b, nullptr, nullptr, qkv2_b, vT, 3072, 1024);
  attn_mfma<<<dim3(16, 16, 2), 512, 0, stream>>>(qkv2_b, vT, mask, attn_b);
  gemm_pipe<false, false, false, false><<<dim3(8, 32), 256, 0, stream>>>(
      attn_b, 1024, outw_b, out_b, nullptr, out, nullptr, nullptr, 1024, 1024);
}

// Round 10
// 293.558 us; speedup vs baseline: 1.0429x; 1.0429x over previous
//
#include <hip/hip_runtime.h>

using u16 = unsigned short;
using u32 = unsigned int;
typedef __attribute__((ext_vector_type(8))) short short8;
typedef __attribute__((ext_vector_type(4))) float f32x4;

#define LOG2E 1.4426950408889634f
#define SCALE2 0.18033688011112042f  // 0.125 * log2(e)

__device__ __forceinline__ u16 f2b(float f) {  // RNE fp32->bf16
  union { float f; unsigned u; } v; v.f = f;
  unsigned r = v.u + 0x7fffu + ((v.u >> 16) & 1u);
  return (u16)(r >> 16);
}

// Raw workgroup barrier: seals LDS ops (lgkmcnt 0) without forcing vmcnt drain.
__device__ __forceinline__ void wg_barrier() {
  asm volatile("s_waitcnt lgkmcnt(0)\n\ts_barrier" ::: "memory");
}

// Direct global->LDS DMA, 16B per lane.
__device__ __forceinline__ void gload_lds16(const void* g, void* l) {
  __builtin_amdgcn_global_load_lds(
      (const __attribute__((address_space(1))) unsigned int*)g,
      (__attribute__((address_space(3))) unsigned int*)l, 16, 0, 0);
}

// ---------------- merged prep: weight pack | rope table | mask transform | layernorm ----------------
__global__ __launch_bounds__(256) void prep(const float* __restrict__ w_qkv, u16* __restrict__ wqkv_b,
                                            const float* __restrict__ in_w, u16* __restrict__ inw_b,
                                            const float* __restrict__ out_w, u16* __restrict__ outw_b,
                                            float2* __restrict__ rtab,
                                            const float* __restrict__ mask, u16* __restrict__ maskp,
                                            const float* __restrict__ x,
                                            const float* __restrict__ ln_g,
                                            const float* __restrict__ ln_b,
                                            u16* __restrict__ xn) {
  __shared__ u16 T[128 * 68];
  __shared__ float sbuf[4], ssbuf[4];
  int blk = blockIdx.x, t = threadIdx.x;
  if (blk < 7168) {            // ---- fp32 -> bf16 weight pack
    int i = blk * 256 + t;
    const float* s; u16* d; int off;
    if (i < 786432)       { s = w_qkv; d = wqkv_b; off = i; }
    else if (i < 1572864) { s = in_w;  d = inw_b;  off = i - 786432; }
    else                  { s = out_w; d = outw_b; off = i - 1572864; }
    float4 v = ((const float4*)s)[off];
    uint2 o;
    o.x = (unsigned)f2b(v.x) | ((unsigned)f2b(v.y) << 16);
    o.y = (unsigned)f2b(v.z) | ((unsigned)f2b(v.w) << 16);
    ((uint2*)d)[off] = o;
  } else if (blk < 11264) {    // ---- RoPE cos/sin table
    int idx = (blk - 7168) * 256 + t;   // 1048576
    int pos = idx >> 9, i = idx & 511;
    float ifreq = exp2f(-(float)(2 * i) * (13.287712379549449f / 1024.0f));
    float ang = (float)pos * ifreq;
    rtab[idx] = make_float2(__cosf(ang), __sinf(ang));
  } else if (blk < 12288) {    // ---- mask -> bf16*log2e in S^T fragment order
    int mb = blk - 11264;      // 0..1023
    int kt = mb & 31, qt = (mb >> 5) & 15, bb = mb >> 9;
    const float* src = mask + ((size_t)bb * 2048 + qt * 128) * 2048 + kt * 64;
    #pragma unroll
    for (int it = 0; it < 8; it++) {
      int id = it * 256 + t;            // 0..2047 float4 groups (128 x 16)
      int r = id >> 4, c4 = (id & 15) * 4;
      float4 v = *(const float4*)(src + (size_t)r * 2048 + c4);
      T[r * 68 + c4 + 0] = f2b(v.x * LOG2E);
      T[r * 68 + c4 + 1] = f2b(v.y * LOG2E);
      T[r * 68 + c4 + 2] = f2b(v.z * LOG2E);
      T[r * 68 + c4 + 3] = f2b(v.w * LOG2E);
    }
    __syncthreads();
    size_t obase = (size_t)(((bb * 16 + qt) * 32) + kt) * 8192;
    #pragma unroll
    for (int it = 0; it < 2; it++) {
      int pos = it * 256 + t;           // 0..511
      int l15 = pos & 15, g = pos >> 4;
      int w = g >> 3, p = (g >> 2) & 1, qd = g & 3;
      int qlocal = w * 32 + p * 16 + l15;
      u16 vals[16];
      #pragma unroll
      for (int mt = 0; mt < 4; mt++)
        #pragma unroll
        for (int reg = 0; reg < 4; reg++)
          vals[mt * 4 + reg] = T[qlocal * 68 + mt * 16 + qd * 4 + reg];
      uint4* dst = (uint4*)(maskp + obase + (size_t)pos * 16);
      dst[0] = *(uint4*)&vals[0];
      dst[1] = *(uint4*)&vals[8];
    }
  } else {                     // ---- LayerNorm rows 0..4095 -> bf16
    int row = blk - 12288;
    const float* xr = x + (size_t)row * 1024;
    float4 v = *(const float4*)(xr + t * 4);
    float s = v.x + v.y + v.z + v.w;
    float ss = v.x * v.x + v.y * v.y + v.z * v.z + v.w * v.w;
    #pragma unroll
    for (int m = 1; m < 64; m <<= 1) {
      s  += __shfl_xor(s, m);
      ss += __shfl_xor(ss, m);
    }
    int wave = t >> 6, lane = t & 63;
    if (lane == 0) { sbuf[wave] = s; ssbuf[wave] = ss; }
    __syncthreads();
    s  = sbuf[0] + sbuf[1] + sbuf[2] + sbuf[3];
    ss = ssbuf[0] + ssbuf[1] + ssbuf[2] + ssbuf[3];
    float mean = s * (1.0f / 1024.0f);
    float var  = ss * (1.0f / 1024.0f) - mean * mean;
    float rstd = 1.0f / sqrtf(var + 1e-5f);
    float4 gv = *(const float4*)(ln_g + t * 4);
    float4 bv = *(const float4*)(ln_b + t * 4);
    uint2 o;
    o.x = (unsigned)f2b((v.x - mean) * rstd * gv.x + bv.x) |
          ((unsigned)f2b((v.y - mean) * rstd * gv.y + bv.y) << 16);
    o.y = (unsigned)f2b((v.z - mean) * rstd * gv.z + bv.z) |
          ((unsigned)f2b((v.w - mean) * rstd * gv.w + bv.w) << 16);
    *(uint2*)(xn + (size_t)row * 1024 + t * 4) = o;
  }
}

// ======== GEMM: BK=32, 3-buffer distance-2 pipeline, global_load_lds DMA
// staging, counted vmcnt(4) at barriers. Linear [128][32] LDS tiles with chunk
// swizzle (both-sides involution). K=1024 assumed (32 tiles). ========
template<bool SLAB, bool OUT_BF16, bool ROPE, bool WVT>
__global__ __launch_bounds__(256, 3) void gemm_pipe(const u16* __restrict__ A, int lda,
                                                    const u16* __restrict__ W,
                                                    const float* __restrict__ bias,
                                                    const float2* __restrict__ rtab,
                                                    float* __restrict__ Cf,
                                                    u16* __restrict__ Cb,
                                                    u16* __restrict__ vT,
                                                    int ldc, int K) {
  __shared__ u16 As[3][128 * 32];
  __shared__ u16 Bs[3][128 * 32];
  int n0 = blockIdx.x * 128, m0 = blockIdx.y * 128;
  int aoff = SLAB ? ((n0 >> 10) << 10) : 0;
  int tid = threadIdx.x;
  int lane = tid & 63, l15 = lane & 15, quad = lane >> 4;
  int w = tid >> 6, mw = w & 1, nw = w >> 1;
  const u16* Abase = A + (size_t)m0 * lda + aoff;
  const u16* Wbase = W + (size_t)n0 * K;
  f32x4 acc[4][4];
  #pragma unroll
  for (int i = 0; i < 4; i++)
    #pragma unroll
    for (int j = 0; j < 4; j++) acc[i][j] = (f32x4){0.f, 0.f, 0.f, 0.f};

  // per-lane DMA source pointers (chunk-swizzled); advance +64B per tile
  int rl = lane >> 2;
  int qs = ((lane & 3) ^ ((lane >> 3) & 3)) * 16;   // byte offset of 16B chunk
  const char* gA0 = (const char*)(Abase + (size_t)(w * 16 + rl) * lda) + qs;
  const char* gA1 = (const char*)(Abase + (size_t)((w + 4) * 16 + rl) * lda) + qs;
  const char* gB0 = (const char*)(Wbase + (size_t)(w * 16 + rl) * K) + qs;
  const char* gB1 = (const char*)(Wbase + (size_t)((w + 4) * 16 + rl) * K) + qs;
  int p16 = (quad ^ ((l15 >> 1) & 3)) * 8;          // u16 offset of swizzled chunk

  #define ISSUE(bf)                                                           \
    gload_lds16(gA0, &As[bf][(w) * 512]);                                     \
    gload_lds16(gA1, &As[bf][(w + 4) * 512]);                                 \
    gload_lds16(gB0, &Bs[bf][(w) * 512]);                                     \
    gload_lds16(gB1, &Bs[bf][(w + 4) * 512]);                                 \
    gA0 += 64; gA1 += 64; gB0 += 64; gB1 += 64;
  #define WBAR4() asm volatile("s_waitcnt vmcnt(4) lgkmcnt(0)\n\ts_barrier" ::: "memory")
  #define WBAR0() asm volatile("s_waitcnt vmcnt(0) lgkmcnt(0)\n\ts_barrier" ::: "memory")
  #define COMPUTE(bf)                                                         \
    {                                                                         \
      short8 af[4], bfr[4];                                                   \
      _Pragma("unroll")                                                       \
      for (int mt = 0; mt < 4; mt++)                                          \
        af[mt] = *(const short8*)&As[bf][(mw * 64 + mt * 16 + l15) * 32 + p16]; \
      _Pragma("unroll")                                                       \
      for (int nt = 0; nt < 4; nt++)                                          \
        bfr[nt] = *(const short8*)&Bs[bf][(nw * 64 + nt * 16 + l15) * 32 + p16]; \
      _Pragma("unroll")                                                       \
      for (int mt = 0; mt < 4; mt++)                                          \
        _Pragma("unroll")                                                     \
        for (int nt = 0; nt < 4; nt++)                                        \
          acc[mt][nt] = __builtin_amdgcn_mfma_f32_16x16x32_bf16(              \
              af[mt], bfr[nt], acc[mt][nt], 0, 0, 0);                         \
    }

  ISSUE(0);            // tile 0
  ISSUE(1);            // tile 1
  WBAR4();             // tile 0 resident
  #pragma unroll 1
  for (int tt = 0; tt < 10; ++tt) {
    ISSUE(2); COMPUTE(0); WBAR4();
    ISSUE(0); COMPUTE(1); WBAR4();
    ISSUE(1); COMPUTE(2); WBAR4();
  }
  COMPUTE(0); WBAR0(); // tile 30; drain tile 31
  COMPUTE(1);          // tile 31
  #undef ISSUE
  #undef WBAR4
  #undef WBAR0
  #undef COMPUTE

  int mb = m0 + mw * 64, nb = n0 + nw * 64;
  float bv[4];
  #pragma unroll
  for (int nt = 0; nt < 4; nt++) bv[nt] = bias[nb + nt * 16 + l15];
  #pragma unroll
  for (int mt = 0; mt < 4; mt++)
    #pragma unroll
    for (int nt = 0; nt < 4; nt++) {
      int col = nb + nt * 16 + l15;
      if (WVT && col >= 2048) {
        // v-columns: write transposed to vT[bb][h][d][s] (4 consecutive s per lane)
        int hh = (col - 2048) >> 6, dd = (col - 2048) & 63;
        int row0 = mb + mt * 16 + quad * 4;
        int bbi = row0 >> 11, s0 = row0 & 2047;
        u16 vv[4];
        #pragma unroll
        for (int reg = 0; reg < 4; reg++) vv[reg] = f2b(acc[mt][nt][reg] + bv[nt]);
        *(uint2*)&vT[((size_t)((bbi * 16 + hh) * 64 + dd)) * 2048 + s0] = *(uint2*)vv;
      } else {
        #pragma unroll
        for (int reg = 0; reg < 4; reg++) {
          int row = mb + mt * 16 + quad * 4 + reg;   // C/D: row=quad*4+reg, col=l15
          float val = acc[mt][nt][reg] + bv[nt];
          if (ROPE && col < 2048) {
            float pr = __shfl_xor(val, 1);
            float2 cs = rtab[(size_t)(row & 2047) * 512 + ((col & 1023) >> 1)];
            val = (col & 1) ? fmaf(val, cs.x, pr * cs.y)
                            : fmaf(val, cs.x, -pr * cs.y);
          }
          if (OUT_BF16) Cb[(size_t)row * ldc + col] = f2b(val);
          else          Cf[(size_t)row * ldc + col] = val;
        }
      }
    }
}

// ---------------- Flash attention: MQ=128, 8 waves = 4 q-groups x 2 k-halves ----------------
// Round-2 verified kernel, verbatim (best measured: 56.3us). Wave (wq,wk) computes
// q rows [wq*32,+32) x k cols [wk*32,+32) per tile; P write->read wave-local;
// O partials + row sums combined across k-waves once at the end.
__global__ __launch_bounds__(512, 4) void attn_mfma(const u16* __restrict__ qkv2,
                                                    const u16* __restrict__ vT,
                                                    const u16* __restrict__ maskp,
                                                    u16* __restrict__ attn_out) {
  __shared__ u16 Kb[2][64 * 72];
  __shared__ u16 Vb[2][64 * 72];
  __shared__ u16 Ps[128 * 72];
  __shared__ float lsf[128];     // [wq][p][l15] row-sum partials from wk=1 waves
  int h = blockIdx.x, qt = blockIdx.y, bb = blockIdx.z;
  int tid = threadIdx.x;
  int lane = tid & 63, l15 = lane & 15, quad = lane >> 4;
  int w = tid >> 6;
  int wq = w & 3, wk = w >> 2;             // q-group 0..3, k-half 0..1
  int sr = tid >> 3, sc = (tid & 7) * 8;   // K/V staging: 1 uint4 per thread (64x64 tile)
  const u16* kslab = qkv2 + ((size_t)bb * 2048) * 3072 + 1024 + h * 64;
  const u16* vslab = vT + ((size_t)((bb * 16 + h) * 64)) * 2048;

  {  // stage Q rows 0..127 (all waves cooperate; barrier below before bq reads)
    int r = tid >> 2, c0 = (tid & 3) * 16;
    const u16* src = qkv2 + (size_t)(bb * 2048 + qt * 128 + r) * 3072 + h * 64 + c0;
    *(uint4*)&Ps[r * 72 + c0]     = *(const uint4*)src;
    *(uint4*)&Ps[r * 72 + c0 + 8] = *(const uint4*)(src + 8);
  }
  {  // stage K/V tile 0
    *(uint4*)&Kb[0][sr * 72 + sc] = *(const uint4*)(kslab + (size_t)sr * 3072 + sc);
    *(uint4*)&Vb[0][sr * 72 + sc] = *(const uint4*)(vslab + (size_t)sr * 2048 + sc);
  }
  // mask fragment base: u16 idx = ((wq*8 + p*4 + quad)*16 + l15)*16 + wk*8  (p=1: +1024)
  const u16* mbase = maskp + ((size_t)((bb * 16 + qt) * 32)) * 8192
                     + ((wq * 8 + quad) * 16 + l15) * 16 + wk * 8;
  uint4 m0 = *(const uint4*)mbase;
  uint4 m1 = *(const uint4*)(mbase + 1024);

  float lsum[2] = {0.f, 0.f};
  f32x4 acc[2][4];
  #pragma unroll
  for (int p = 0; p < 2; p++)
    #pragma unroll
    for (int dt = 0; dt < 4; dt++) acc[p][dt] = (f32x4){0.f, 0.f, 0.f, 0.f};
  wg_barrier();

  short8 bq[2][2];
  #pragma unroll
  for (int p = 0; p < 2; p++)
    #pragma unroll
    for (int hk = 0; hk < 2; hk++)
      bq[p][hk] = *(const short8*)&Ps[(wq * 32 + p * 16 + l15) * 72 + hk * 32 + quad * 8];

  for (int kt = 0; kt < 32; kt++) {
    int b = kt & 1;
    uint4 kr, vr, m0n, m1n;
    if (kt + 1 < 32) {  // prefetch next K/V tile and next mask fragments
      kr = *(const uint4*)(kslab + (size_t)((kt + 1) * 64 + sr) * 3072 + sc);
      vr = *(const uint4*)(vslab + (size_t)sr * 2048 + (kt + 1) * 64 + sc);
      m0n = *(const uint4*)(mbase + (size_t)(kt + 1) * 8192);
      m1n = *(const uint4*)(mbase + (size_t)(kt + 1) * 8192 + 1024);
    }
    short8 ak[2][2];
    #pragma unroll
    for (int mt = 0; mt < 2; mt++)
      #pragma unroll
      for (int hk = 0; hk < 2; hk++)
        ak[mt][hk] = *(const short8*)&Kb[b][(wk * 32 + mt * 16 + l15) * 72 + hk * 32 + quad * 8];
    f32x4 st[2][2];
    #pragma unroll
    for (int p = 0; p < 2; p++)
      #pragma unroll
      for (int mt = 0; mt < 2; mt++) {
        f32x4 z = (f32x4){0.f, 0.f, 0.f, 0.f};
        z = __builtin_amdgcn_mfma_f32_16x16x32_bf16(ak[mt][0], bq[p][0], z, 0, 0, 0);
        st[p][mt] = __builtin_amdgcn_mfma_f32_16x16x32_bf16(ak[mt][1], bq[p][1], z, 0, 0, 0);
      }
    #pragma unroll
    for (int p = 0; p < 2; p++) {
      uint4 mm = p ? m1 : m0;
      u32 wds[4] = {mm.x, mm.y, mm.z, mm.w};
      float mv[8];
      #pragma unroll
      for (int j = 0; j < 4; j++) {
        mv[2 * j]     = __uint_as_float(wds[j] << 16);
        mv[2 * j + 1] = __uint_as_float(wds[j] & 0xffff0000u);
      }
      int prow = (wq * 32 + p * 16 + l15) * 72 + wk * 32 + quad * 4;
      #pragma unroll
      for (int mt = 0; mt < 2; mt++) {
        float sv0 = fmaf(st[p][mt][0], SCALE2, mv[mt * 4 + 0]);
        float sv1 = fmaf(st[p][mt][1], SCALE2, mv[mt * 4 + 1]);
        float sv2 = fmaf(st[p][mt][2], SCALE2, mv[mt * 4 + 2]);
        float sv3 = fmaf(st[p][mt][3], SCALE2, mv[mt * 4 + 3]);
        float p0 = __builtin_amdgcn_exp2f(sv0), p1 = __builtin_amdgcn_exp2f(sv1);
        float p2 = __builtin_amdgcn_exp2f(sv2), p3 = __builtin_amdgcn_exp2f(sv3);
        lsum[p] += (p0 + p1) + (p2 + p3);
        u32 pk0, pk1;
        asm("v_cvt_pk_bf16_f32 %0, %1, %2" : "=v"(pk0) : "v"(p0), "v"(p1));
        asm("v_cvt_pk_bf16_f32 %0, %1, %2" : "=v"(pk1) : "v"(p2), "v"(p3));
        *(uint2*)&Ps[prow + mt * 16] = make_uint2(pk0, pk1);
      }
    }
    short8 ap[2];
    #pragma unroll
    for (int p = 0; p < 2; p++)
      ap[p] = *(const short8*)&Ps[(wq * 32 + p * 16 + l15) * 72 + wk * 32 + quad * 8];
    #pragma unroll
    for (int dt = 0; dt < 4; dt++) {
      short8 bv = *(const short8*)&Vb[b][(dt * 16 + l15) * 72 + wk * 32 + quad * 8];
      #pragma unroll
      for (int p = 0; p < 2; p++)
        acc[p][dt] = __builtin_amdgcn_mfma_f32_16x16x32_bf16(ap[p], bv, acc[p][dt], 0, 0, 0);
    }
    if (kt + 1 < 32) {
      int nb = b ^ 1;
      *(uint4*)&Kb[nb][sr * 72 + sc] = kr;
      *(uint4*)&Vb[nb][sr * 72 + sc] = vr;
      m0 = m0n; m1 = m1n;
    }
    wg_barrier();
  }

  // ---- cross-k-wave combine: wk=1 dumps O-partials + row sums; wk=0 merges ----
  float* fs = ((wq < 2) ? (float*)&Kb[0][0] : (float*)&Vb[0][0]) + (wq & 1) * 2176;
  if (wk) {
    #pragma unroll
    for (int p = 0; p < 2; p++) {
      #pragma unroll
      for (int dt = 0; dt < 4; dt++)
        #pragma unroll
        for (int reg = 0; reg < 4; reg++)
          fs[(p * 16 + quad * 4 + reg) * 68 + dt * 16 + l15] = acc[p][dt][reg];
      float l = lsum[p];
      l += __shfl_xor(l, 16);
      l += __shfl_xor(l, 32);
      if (lane < 16) lsf[(wq * 2 + p) * 16 + l15] = l;
    }
  }
  wg_barrier();
  if (!wk) {
    #pragma unroll
    for (int p = 0; p < 2; p++) {
      float l = lsum[p];
      l += __shfl_xor(l, 16);
      l += __shfl_xor(l, 32);
      l += lsf[(wq * 2 + p) * 16 + l15];     // full row sum for q = l15 (local)
      #pragma unroll
      for (int reg = 0; reg < 4; reg++) {
        float lq = __shfl(l, quad * 4 + reg);
        float inv = 1.0f / lq;
        int grow = bb * 2048 + qt * 128 + wq * 32 + p * 16 + quad * 4 + reg;
        #pragma unroll
        for (int dt = 0; dt < 4; dt++) {
          float o = acc[p][dt][reg] + fs[(p * 16 + quad * 4 + reg) * 68 + dt * 16 + l15];
          attn_out[(size_t)grow * 1024 + h * 64 + dt * 16 + l15] = f2b(o * inv);
        }
      }
    }
  }
}

extern "C" void kernel_launch(void* const* d_in, const int* in_sizes, int n_in,
                              void* d_out, int out_size, void* d_ws, size_t ws_size,
                              hipStream_t stream) {
  const float* x     = (const float*)d_in[0];
  const float* mask  = (const float*)d_in[1];
  const float* ln_g  = (const float*)d_in[2];
  const float* ln_b  = (const float*)d_in[3];
  const float* w_qkv = (const float*)d_in[4];
  const float* b_qkv = (const float*)d_in[5];
  const float* in_w  = (const float*)d_in[6];
  const float* in_b  = (const float*)d_in[7];
  const float* out_w = (const float*)d_in[8];
  const float* out_b = (const float*)d_in[9];
  float* out = (float*)d_out;
  char* ws = (char*)d_ws;

  u16* wqkv_b = (u16*)(ws);                   //  6291456  (3072x1024)
  u16* inw_b  = (u16*)(ws + 6291456ull);      //  6291456  (3072x1024)
  u16* outw_b = (u16*)(ws + 12582912ull);     //  2097152  (1024x1024)
  u16* xn_b   = (u16*)(ws + 14680064ull);     //  8388608  (4096x1024)
  u16* attn_b = xn_b;                         //  reuse (xn dead after gemm1)
  u16* qkv_b  = (u16*)(ws + 23068672ull);     // 25165824  (4096x3072)
  u16* qkv2_b = (u16*)(ws + 48234496ull);     // 25165824  (4096x3072; v cols unused)
  float2* rtab = (float2*)qkv2_b;             //  8388608  aliases qkv2 (dead before gemm2)
  u16* vT     = (u16*)(ws + 73400320ull);     //  8388608  (2,16,64,2048)
  u16* maskp  = (u16*)(ws + 81788928ull);     // 16777216  (2*16*32 tiles * 8192 u16)

  prep<<<16384, 256, 0, stream>>>(w_qkv, wqkv_b, in_w, inw_b, out_w, outw_b,
                                  rtab, mask, maskp, x, ln_g, ln_b, xn_b);
  gemm_pipe<false, true, true, false><<<dim3(24, 32), 256, 0, stream>>>(
      xn_b, 1024, wqkv_b, b_qkv, rtab, nullptr, qkv_b, nullptr, 3072, 1024);
  gemm_pipe<true, true, false, true><<<dim3(24, 32), 256, 0, stream>>>(
      qkv_b, 3072, inw_b, in_b, nullptr, nullptr, qkv2_b, vT, 3072, 1024);
  attn_mfma<<<dim3(16, 16, 2), 512, 0, stream>>>(qkv2_b, vT, maskp, attn_b);
  gemm_pipe<false, false, false, false><<<dim3(8, 32), 256, 0, stream>>>(
      attn_b, 1024, outw_b, out_b, nullptr, out, nullptr, nullptr, 1024, 1024);
}

// Round 12
// 291.597 us; speedup vs baseline: 1.0499x; 1.0067x over previous
//
#include <hip/hip_runtime.h>

using u16 = unsigned short;
using u32 = unsigned int;
typedef __attribute__((ext_vector_type(8))) short short8;
typedef __attribute__((ext_vector_type(4))) float f32x4;

#define LOG2E 1.4426950408889634f
#define SCALE2 0.18033688011112042f  // 0.125 * log2(e)

__device__ __forceinline__ u16 f2b(float f) {  // RNE fp32->bf16
  union { float f; unsigned u; } v; v.f = f;
  unsigned r = v.u + 0x7fffu + ((v.u >> 16) & 1u);
  return (u16)(r >> 16);
}

// Raw workgroup barrier: seals LDS ops (lgkmcnt 0) without forcing vmcnt drain.
__device__ __forceinline__ void wg_barrier() {
  asm volatile("s_waitcnt lgkmcnt(0)\n\ts_barrier" ::: "memory");
}

// Direct global->LDS DMA, 16B per lane.
__device__ __forceinline__ void gload_lds16(const void* g, void* l) {
  __builtin_amdgcn_global_load_lds(
      (const __attribute__((address_space(1))) unsigned int*)g,
      (__attribute__((address_space(3))) unsigned int*)l, 16, 0, 0);
}

// ---------------- merged prep: weight pack | rope table | mask transform | layernorm ----------------
__global__ __launch_bounds__(256) void prep(const float* __restrict__ w_qkv, u16* __restrict__ wqkv_b,
                                            const float* __restrict__ in_w, u16* __restrict__ inw_b,
                                            const float* __restrict__ out_w, u16* __restrict__ outw_b,
                                            float2* __restrict__ rtab,
                                            const float* __restrict__ mask, u16* __restrict__ maskp,
                                            const float* __restrict__ x,
                                            const float* __restrict__ ln_g,
                                            const float* __restrict__ ln_b,
                                            u16* __restrict__ xn) {
  __shared__ u16 T[128 * 68];
  __shared__ float sbuf[4], ssbuf[4];
  int blk = blockIdx.x, t = threadIdx.x;
  if (blk < 7168) {            // ---- fp32 -> bf16 weight pack
    int i = blk * 256 + t;
    const float* s; u16* d; int off;
    if (i < 786432)       { s = w_qkv; d = wqkv_b; off = i; }
    else if (i < 1572864) { s = in_w;  d = inw_b;  off = i - 786432; }
    else                  { s = out_w; d = outw_b; off = i - 1572864; }
    float4 v = ((const float4*)s)[off];
    uint2 o;
    o.x = (unsigned)f2b(v.x) | ((unsigned)f2b(v.y) << 16);
    o.y = (unsigned)f2b(v.z) | ((unsigned)f2b(v.w) << 16);
    ((uint2*)d)[off] = o;
  } else if (blk < 11264) {    // ---- RoPE cos/sin table
    int idx = (blk - 7168) * 256 + t;   // 1048576
    int pos = idx >> 9, i = idx & 511;
    float ifreq = exp2f(-(float)(2 * i) * (13.287712379549449f / 1024.0f));
    float ang = (float)pos * ifreq;
    rtab[idx] = make_float2(__cosf(ang), __sinf(ang));
  } else if (blk < 12288) {    // ---- mask -> bf16*log2e in S^T fragment order
    int mb = blk - 11264;      // 0..1023
    int kt = mb & 31, qt = (mb >> 5) & 15, bb = mb >> 9;
    const float* src = mask + ((size_t)bb * 2048 + qt * 128) * 2048 + kt * 64;
    #pragma unroll
    for (int it = 0; it < 8; it++) {
      int id = it * 256 + t;            // 0..2047 float4 groups (128 x 16)
      int r = id >> 4, c4 = (id & 15) * 4;
      float4 v = *(const float4*)(src + (size_t)r * 2048 + c4);
      T[r * 68 + c4 + 0] = f2b(v.x * LOG2E);
      T[r * 68 + c4 + 1] = f2b(v.y * LOG2E);
      T[r * 68 + c4 + 2] = f2b(v.z * LOG2E);
      T[r * 68 + c4 + 3] = f2b(v.w * LOG2E);
    }
    __syncthreads();
    size_t obase = (size_t)(((bb * 16 + qt) * 32) + kt) * 8192;
    #pragma unroll
    for (int it = 0; it < 2; it++) {
      int pos = it * 256 + t;           // 0..511
      int l15 = pos & 15, g = pos >> 4;
      int w = g >> 3, p = (g >> 2) & 1, qd = g & 3;
      int qlocal = w * 32 + p * 16 + l15;
      u16 vals[16];
      #pragma unroll
      for (int mt = 0; mt < 4; mt++)
        #pragma unroll
        for (int reg = 0; reg < 4; reg++)
          vals[mt * 4 + reg] = T[qlocal * 68 + mt * 16 + qd * 4 + reg];
      uint4* dst = (uint4*)(maskp + obase + (size_t)pos * 16);
      dst[0] = *(uint4*)&vals[0];
      dst[1] = *(uint4*)&vals[8];
    }
  } else {                     // ---- LayerNorm rows 0..4095 -> bf16
    int row = blk - 12288;
    const float* xr = x + (size_t)row * 1024;
    float4 v = *(const float4*)(xr + t * 4);
    float s = v.x + v.y + v.z + v.w;
    float ss = v.x * v.x + v.y * v.y + v.z * v.z + v.w * v.w;
    #pragma unroll
    for (int m = 1; m < 64; m <<= 1) {
      s  += __shfl_xor(s, m);
      ss += __shfl_xor(ss, m);
    }
    int wave = t >> 6, lane = t & 63;
    if (lane == 0) { sbuf[wave] = s; ssbuf[wave] = ss; }
    __syncthreads();
    s  = sbuf[0] + sbuf[1] + sbuf[2] + sbuf[3];
    ss = ssbuf[0] + ssbuf[1] + ssbuf[2] + ssbuf[3];
    float mean = s * (1.0f / 1024.0f);
    float var  = ss * (1.0f / 1024.0f) - mean * mean;
    float rstd = 1.0f / sqrtf(var + 1e-5f);
    float4 gv = *(const float4*)(ln_g + t * 4);
    float4 bv = *(const float4*)(ln_b + t * 4);
    uint2 o;
    o.x = (unsigned)f2b((v.x - mean) * rstd * gv.x + bv.x) |
          ((unsigned)f2b((v.y - mean) * rstd * gv.y + bv.y) << 16);
    o.y = (unsigned)f2b((v.z - mean) * rstd * gv.z + bv.z) |
          ((unsigned)f2b((v.w - mean) * rstd * gv.w + bv.w) << 16);
    *(uint2*)(xn + (size_t)row * 1024 + t * 4) = o;
  }
}

// ======== GEMM: BK=32, 3-buffer distance-2 pipeline, global_load_lds DMA
// staging, counted vmcnt(4) at barriers. Linear [128][32] LDS tiles with chunk
// swizzle (both-sides involution). K=1024 assumed (32 tiles). ========
template<bool SLAB, bool OUT_BF16, bool ROPE, bool WVT>
__global__ __launch_bounds__(256, 3) void gemm_pipe(const u16* __restrict__ A, int lda,
                                                    const u16* __restrict__ W,
                                                    const float* __restrict__ bias,
                                                    const float2* __restrict__ rtab,
                                                    float* __restrict__ Cf,
                                                    u16* __restrict__ Cb,
                                                    u16* __restrict__ vT,
                                                    int ldc, int K) {
  __shared__ u16 As[3][128 * 32];
  __shared__ u16 Bs[3][128 * 32];
  int n0 = blockIdx.x * 128, m0 = blockIdx.y * 128;
  int aoff = SLAB ? ((n0 >> 10) << 10) : 0;
  int tid = threadIdx.x;
  int lane = tid & 63, l15 = lane & 15, quad = lane >> 4;
  int w = tid >> 6, mw = w & 1, nw = w >> 1;
  const u16* Abase = A + (size_t)m0 * lda + aoff;
  const u16* Wbase = W + (size_t)n0 * K;
  f32x4 acc[4][4];
  #pragma unroll
  for (int i = 0; i < 4; i++)
    #pragma unroll
    for (int j = 0; j < 4; j++) acc[i][j] = (f32x4){0.f, 0.f, 0.f, 0.f};

  // per-lane DMA source pointers (chunk-swizzled); advance +64B per tile
  int rl = lane >> 2;
  int qs = ((lane & 3) ^ ((lane >> 3) & 3)) * 16;   // byte offset of 16B chunk
  const char* gA0 = (const char*)(Abase + (size_t)(w * 16 + rl) * lda) + qs;
  const char* gA1 = (const char*)(Abase + (size_t)((w + 4) * 16 + rl) * lda) + qs;
  const char* gB0 = (const char*)(Wbase + (size_t)(w * 16 + rl) * K) + qs;
  const char* gB1 = (const char*)(Wbase + (size_t)((w + 4) * 16 + rl) * K) + qs;
  int p16 = (quad ^ ((l15 >> 1) & 3)) * 8;          // u16 offset of swizzled chunk

  #define ISSUE(bf)                                                           \
    gload_lds16(gA0, &As[bf][(w) * 512]);                                     \
    gload_lds16(gA1, &As[bf][(w + 4) * 512]);                                 \
    gload_lds16(gB0, &Bs[bf][(w) * 512]);                                     \
    gload_lds16(gB1, &Bs[bf][(w + 4) * 512]);                                 \
    gA0 += 64; gA1 += 64; gB0 += 64; gB1 += 64;
  #define WBAR4() asm volatile("s_waitcnt vmcnt(4) lgkmcnt(0)\n\ts_barrier" ::: "memory")
  #define WBAR0() asm volatile("s_waitcnt vmcnt(0) lgkmcnt(0)\n\ts_barrier" ::: "memory")
  #define COMPUTE(bf)                                                         \
    {                                                                         \
      short8 af[4], bfr[4];                                                   \
      _Pragma("unroll")                                                       \
      for (int mt = 0; mt < 4; mt++)                                          \
        af[mt] = *(const short8*)&As[bf][(mw * 64 + mt * 16 + l15) * 32 + p16]; \
      _Pragma("unroll")                                                       \
      for (int nt = 0; nt < 4; nt++)                                          \
        bfr[nt] = *(const short8*)&Bs[bf][(nw * 64 + nt * 16 + l15) * 32 + p16]; \
      _Pragma("unroll")                                                       \
      for (int mt = 0; mt < 4; mt++)                                          \
        _Pragma("unroll")                                                     \
        for (int nt = 0; nt < 4; nt++)                                        \
          acc[mt][nt] = __builtin_amdgcn_mfma_f32_16x16x32_bf16(              \
              af[mt], bfr[nt], acc[mt][nt], 0, 0, 0);                         \
    }

  ISSUE(0);            // tile 0
  ISSUE(1);            // tile 1
  WBAR4();             // tile 0 resident
  #pragma unroll 1
  for (int tt = 0; tt < 10; ++tt) {
    ISSUE(2); COMPUTE(0); WBAR4();
    ISSUE(0); COMPUTE(1); WBAR4();
    ISSUE(1); COMPUTE(2); WBAR4();
  }
  COMPUTE(0); WBAR0(); // tile 30; drain tile 31
  COMPUTE(1);          // tile 31
  #undef ISSUE
  #undef WBAR4
  #undef WBAR0
  #undef COMPUTE

  int mb = m0 + mw * 64, nb = n0 + nw * 64;
  float bv[4];
  #pragma unroll
  for (int nt = 0; nt < 4; nt++) bv[nt] = bias[nb + nt * 16 + l15];
  #pragma unroll
  for (int mt = 0; mt < 4; mt++)
    #pragma unroll
    for (int nt = 0; nt < 4; nt++) {
      int col = nb + nt * 16 + l15;
      if (WVT && col >= 2048) {
        // v-columns: write transposed to vT[bb][h][d][s] (4 consecutive s per lane)
        int hh = (col - 2048) >> 6, dd = (col - 2048) & 63;
        int row0 = mb + mt * 16 + quad * 4;
        int bbi = row0 >> 11, s0 = row0 & 2047;
        u16 vv[4];
        #pragma unroll
        for (int reg = 0; reg < 4; reg++) vv[reg] = f2b(acc[mt][nt][reg] + bv[nt]);
        *(uint2*)&vT[((size_t)((bbi * 16 + hh) * 64 + dd)) * 2048 + s0] = *(uint2*)vv;
      } else {
        #pragma unroll
        for (int reg = 0; reg < 4; reg++) {
          int row = mb + mt * 16 + quad * 4 + reg;   // C/D: row=quad*4+reg, col=l15
          float val = acc[mt][nt][reg] + bv[nt];
          if (ROPE && col < 2048) {
            float pr = __shfl_xor(val, 1);
            float2 cs = rtab[(size_t)(row & 2047) * 512 + ((col & 1023) >> 1)];
            val = (col & 1) ? fmaf(val, cs.x, pr * cs.y)
                            : fmaf(val, cs.x, -pr * cs.y);
          }
          if (OUT_BF16) Cb[(size_t)row * ldc + col] = f2b(val);
          else          Cf[(size_t)row * ldc + col] = val;
        }
      }
    }
}

// ---------------- Flash attention: MQ=128, 8 waves = 4 q-groups x 2 k-halves ----------------
// Round-2 verified kernel, verbatim (best measured: 56.3us). Wave (wq,wk) computes
// q rows [wq*32,+32) x k cols [wk*32,+32) per tile; P write->read wave-local;
// O partials + row sums combined across k-waves once at the end.
__global__ __launch_bounds__(512, 4) void attn_mfma(const u16* __restrict__ qkv2,
                                                    const u16* __restrict__ vT,
                                                    const u16* __restrict__ maskp,
                                                    u16* __restrict__ attn_out) {
  __shared__ u16 Kb[2][64 * 72];
  __shared__ u16 Vb[2][64 * 72];
  __shared__ u16 Ps[128 * 72];
  __shared__ float lsf[128];     // [wq][p][l15] row-sum partials from wk=1 waves
  int h = blockIdx.x, qt = blockIdx.y, bb = blockIdx.z;
  int tid = threadIdx.x;
  int lane = tid & 63, l15 = lane & 15, quad = lane >> 4;
  int w = tid >> 6;
  int wq = w & 3, wk = w >> 2;             // q-group 0..3, k-half 0..1
  int sr = tid >> 3, sc = (tid & 7) * 8;   // K/V staging: 1 uint4 per thread (64x64 tile)
  const u16* kslab = qkv2 + ((size_t)bb * 2048) * 3072 + 1024 + h * 64;
  const u16* vslab = vT + ((size_t)((bb * 16 + h) * 64)) * 2048;

  {  // stage Q rows 0..127 (all waves cooperate; barrier below before bq reads)
    int r = tid >> 2, c0 = (tid & 3) * 16;
    const u16* src = qkv2 + (size_t)(bb * 2048 + qt * 128 + r) * 3072 + h * 64 + c0;
    *(uint4*)&Ps[r * 72 + c0]     = *(const uint4*)src;
    *(uint4*)&Ps[r * 72 + c0 + 8] = *(const uint4*)(src + 8);
  }
  {  // stage K/V tile 0
    *(uint4*)&Kb[0][sr * 72 + sc] = *(const uint4*)(kslab + (size_t)sr * 3072 + sc);
    *(uint4*)&Vb[0][sr * 72 + sc] = *(const uint4*)(vslab + (size_t)sr * 2048 + sc);
  }
  // mask fragment base: u16 idx = ((wq*8 + p*4 + quad)*16 + l15)*16 + wk*8  (p=1: +1024)
  const u16* mbase = maskp + ((size_t)((bb * 16 + qt) * 32)) * 8192
                     + ((wq * 8 + quad) * 16 + l15) * 16 + wk * 8;
  uint4 m0 = *(const uint4*)mbase;
  uint4 m1 = *(const uint4*)(mbase + 1024);

  float lsum[2] = {0.f, 0.f};
  f32x4 acc[2][4];
  #pragma unroll
  for (int p = 0; p < 2; p++)
    #pragma unroll
    for (int dt = 0; dt < 4; dt++) acc[p][dt] = (f32x4){0.f, 0.f, 0.f, 0.f};
  wg_barrier();

  short8 bq[2][2];
  #pragma unroll
  for (int p = 0; p < 2; p++)
    #pragma unroll
    for (int hk = 0; hk < 2; hk++)
      bq[p][hk] = *(const short8*)&Ps[(wq * 32 + p * 16 + l15) * 72 + hk * 32 + quad * 8];

  for (int kt = 0; kt < 32; kt++) {
    int b = kt & 1;
    uint4 kr, vr, m0n, m1n;
    if (kt + 1 < 32) {  // prefetch next K/V tile and next mask fragments
      kr = *(const uint4*)(kslab + (size_t)((kt + 1) * 64 + sr) * 3072 + sc);
      vr = *(const uint4*)(vslab + (size_t)sr * 2048 + (kt + 1) * 64 + sc);
      m0n = *(const uint4*)(mbase + (size_t)(kt + 1) * 8192);
      m1n = *(const uint4*)(mbase + (size_t)(kt + 1) * 8192 + 1024);
    }
    short8 ak[2][2];
    #pragma unroll
    for (int mt = 0; mt < 2; mt++)
      #pragma unroll
      for (int hk = 0; hk < 2; hk++)
        ak[mt][hk] = *(const short8*)&Kb[b][(wk * 32 + mt * 16 + l15) * 72 + hk * 32 + quad * 8];
    f32x4 st[2][2];
    #pragma unroll
    for (int p = 0; p < 2; p++)
      #pragma unroll
      for (int mt = 0; mt < 2; mt++) {
        f32x4 z = (f32x4){0.f, 0.f, 0.f, 0.f};
        z = __builtin_amdgcn_mfma_f32_16x16x32_bf16(ak[mt][0], bq[p][0], z, 0, 0, 0);
        st[p][mt] = __builtin_amdgcn_mfma_f32_16x16x32_bf16(ak[mt][1], bq[p][1], z, 0, 0, 0);
      }
    #pragma unroll
    for (int p = 0; p < 2; p++) {
      uint4 mm = p ? m1 : m0;
      u32 wds[4] = {mm.x, mm.y, mm.z, mm.w};
      float mv[8];
      #pragma unroll
      for (int j = 0; j < 4; j++) {
        mv[2 * j]     = __uint_as_float(wds[j] << 16);
        mv[2 * j + 1] = __uint_as_float(wds[j] & 0xffff0000u);
      }
      int prow = (wq * 32 + p * 16 + l15) * 72 + wk * 32 + quad * 4;
      #pragma unroll
      for (int mt = 0; mt < 2; mt++) {
        float sv0 = fmaf(st[p][mt][0], SCALE2, mv[mt * 4 + 0]);
        float sv1 = fmaf(st[p][mt][1], SCALE2, mv[mt * 4 + 1]);
        float sv2 = fmaf(st[p][mt][2], SCALE2, mv[mt * 4 + 2]);
        float sv3 = fmaf(st[p][mt][3], SCALE2, mv[mt * 4 + 3]);
        float p0 = __builtin_amdgcn_exp2f(sv0), p1 = __builtin_amdgcn_exp2f(sv1);
        float p2 = __builtin_amdgcn_exp2f(sv2), p3 = __builtin_amdgcn_exp2f(sv3);
        lsum[p] += (p0 + p1) + (p2 + p3);
        u32 pk0, pk1;
        asm("v_cvt_pk_bf16_f32 %0, %1, %2" : "=v"(pk0) : "v"(p0), "v"(p1));
        asm("v_cvt_pk_bf16_f32 %0, %1, %2" : "=v"(pk1) : "v"(p2), "v"(p3));
        *(uint2*)&Ps[prow + mt * 16] = make_uint2(pk0, pk1);
      }
    }
    short8 ap[2];
    #pragma unroll
    for (int p = 0; p < 2; p++)
      ap[p] = *(const short8*)&Ps[(wq * 32 + p * 16 + l15) * 72 + wk * 32 + quad * 8];
    #pragma unroll
    for (int dt = 0; dt < 4; dt++) {
      short8 bv = *(const short8*)&Vb[b][(dt * 16 + l15) * 72 + wk * 32 + quad * 8];
      #pragma unroll
      for (int p = 0; p < 2; p++)
        acc[p][dt] = __builtin_amdgcn_mfma_f32_16x16x32_bf16(ap[p], bv, acc[p][dt], 0, 0, 0);
    }
    if (kt + 1 < 32) {
      int nb = b ^ 1;
      *(uint4*)&Kb[nb][sr * 72 + sc] = kr;
      *(uint4*)&Vb[nb][sr * 72 + sc] = vr;
      m0 = m0n; m1 = m1n;
    }
    wg_barrier();
  }

  // ---- cross-k-wave combine: wk=1 dumps O-partials + row sums; wk=0 merges ----
  float* fs = ((wq < 2) ? (float*)&Kb[0][0] : (float*)&Vb[0][0]) + (wq & 1) * 2176;
  if (wk) {
    #pragma unroll
    for (int p = 0; p < 2; p++) {
      #pragma unroll
      for (int dt = 0; dt < 4; dt++)
        #pragma unroll
        for (int reg = 0; reg < 4; reg++)
          fs[(p * 16 + quad * 4 + reg) * 68 + dt * 16 + l15] = acc[p][dt][reg];
      float l = lsum[p];
      l += __shfl_xor(l, 16);
      l += __shfl_xor(l, 32);
      if (lane < 16) lsf[(wq * 2 + p) * 16 + l15] = l;
    }
  }
  wg_barrier();
  if (!wk) {
    #pragma unroll
    for (int p = 0; p < 2; p++) {
      float l = lsum[p];
      l += __shfl_xor(l, 16);
      l += __shfl_xor(l, 32);
      l += lsf[(wq * 2 + p) * 16 + l15];     // full row sum for q = l15 (local)
      #pragma unroll
      for (int reg = 0; reg < 4; reg++) {
        float lq = __shfl(l, quad * 4 + reg);
        float inv = 1.0f / lq;
        int grow = bb * 2048 + qt * 128 + wq * 32 + p * 16 + quad * 4 + reg;
        #pragma unroll
        for (int dt = 0; dt < 4; dt++) {
          float o = acc[p][dt][reg] + fs[(p * 16 + quad * 4 + reg) * 68 + dt * 16 + l15];
          attn_out[(size_t)grow * 1024 + h * 64 + dt * 16 + l15] = f2b(o * inv);
        }
      }
    }
  }
}

extern "C" void kernel_launch(void* const* d_in, const int* in_sizes, int n_in,
                              void* d_out, int out_size, void* d_ws, size_t ws_size,
                              hipStream_t stream) {
  const float* x     = (const float*)d_in[0];
  const float* mask  = (const float*)d_in[1];
  const float* ln_g  = (const float*)d_in[2];
  const float* ln_b  = (const float*)d_in[3];
  const float* w_qkv = (const float*)d_in[4];
  const float* b_qkv = (const float*)d_in[5];
  const float* in_w  = (const float*)d_in[6];
  const float* in_b  = (const float*)d_in[7];
  const float* out_w = (const float*)d_in[8];
  const float* out_b = (const float*)d_in[9];
  float* out = (float*)d_out;
  char* ws = (char*)d_ws;

  u16* wqkv_b = (u16*)(ws);                   //  6291456  (3072x1024)
  u16* inw_b  = (u16*)(ws + 6291456ull);      //  6291456  (3072x1024)
  u16* outw_b = (u16*)(ws + 12582912ull);     //  2097152  (1024x1024)
  u16* xn_b   = (u16*)(ws + 14680064ull);     //  8388608  (4096x1024)
  u16* attn_b = xn_b;                         //  reuse (xn dead after gemm1)
  u16* qkv_b  = (u16*)(ws + 23068672ull);     // 25165824  (4096x3072)
  u16* qkv2_b = (u16*)(ws + 48234496ull);     // 25165824  (4096x3072; v cols unused)
  float2* rtab = (float2*)qkv2_b;             //  8388608  aliases qkv2 (dead before gemm2)
  u16* vT     = (u16*)(ws + 73400320ull);     //  8388608  (2,16,64,2048)
  u16* maskp  = (u16*)(ws + 81788928ull);     // 16777216  (2*16*32 tiles * 8192 u16)

  prep<<<16384, 256, 0, stream>>>(w_qkv, wqkv_b, in_w, inw_b, out_w, outw_b,
                                  rtab, mask, maskp, x, ln_g, ln_b, xn_b);
  gemm_pipe<false, true, true, false><<<dim3(24, 32), 256, 0, stream>>>(
      xn_b, 1024, wqkv_b, b_qkv, rtab, nullptr, qkv_b, nullptr, 3072, 1024);
  gemm_pipe<true, true, false, true><<<dim3(24, 32), 256, 0, stream>>>(
      qkv_b, 3072, inw_b, in_b, nullptr, nullptr, qkv2_b, vT, 3072, 1024);
  attn_mfma<<<dim3(16, 16, 2), 512, 0, stream>>>(qkv2_b, vT, maskp, attn_b);
  gemm_pipe<false, false, false, false><<<dim3(8, 32), 256, 0, stream>>>(
      attn_b, 1024, outw_b, out_b, nullptr, out, nullptr, nullptr, 1024, 1024);
}

// Round 13
// 289.070 us; speedup vs baseline: 1.0591x; 1.0087x over previous
//
#include <hip/hip_runtime.h>

using u16 = unsigned short;
using u32 = unsigned int;
typedef __attribute__((ext_vector_type(8))) short short8;
typedef __attribute__((ext_vector_type(4))) float f32x4;

#define LOG2E 1.4426950408889634f
#define SCALE2 0.18033688011112042f  // 0.125 * log2(e)

__device__ __forceinline__ u16 f2b(float f) {  // RNE fp32->bf16
  union { float f; unsigned u; } v; v.f = f;
  unsigned r = v.u + 0x7fffu + ((v.u >> 16) & 1u);
  return (u16)(r >> 16);
}

// Raw workgroup barrier: seals LDS ops (lgkmcnt 0) without forcing vmcnt drain.
__device__ __forceinline__ void wg_barrier() {
  asm volatile("s_waitcnt lgkmcnt(0)\n\ts_barrier" ::: "memory");
}

// Direct global->LDS DMA, 16B per lane.
__device__ __forceinline__ void gload_lds16(const void* g, void* l) {
  __builtin_amdgcn_global_load_lds(
      (const __attribute__((address_space(1))) unsigned int*)g,
      (__attribute__((address_space(3))) unsigned int*)l, 16, 0, 0);
}

// ---------------- merged prep: weight pack | rope table | mask transform | layernorm ----------------
__global__ __launch_bounds__(256) void prep(const float* __restrict__ w_qkv, u16* __restrict__ wqkv_b,
                                            const float* __restrict__ in_w, u16* __restrict__ inw_b,
                                            const float* __restrict__ out_w, u16* __restrict__ outw_b,
                                            float2* __restrict__ rtab,
                                            const float* __restrict__ mask, u16* __restrict__ maskp,
                                            const float* __restrict__ x,
                                            const float* __restrict__ ln_g,
                                            const float* __restrict__ ln_b,
                                            u16* __restrict__ xn) {
  __shared__ u16 T[128 * 68];
  __shared__ float sbuf[4], ssbuf[4];
  int blk = blockIdx.x, t = threadIdx.x;
  if (blk < 7168) {            // ---- fp32 -> bf16 weight pack
    int i = blk * 256 + t;
    const float* s; u16* d; int off;
    if (i < 786432)       { s = w_qkv; d = wqkv_b; off = i; }
    else if (i < 1572864) { s = in_w;  d = inw_b;  off = i - 786432; }
    else                  { s = out_w; d = outw_b; off = i - 1572864; }
    float4 v = ((const float4*)s)[off];
    uint2 o;
    o.x = (unsigned)f2b(v.x) | ((unsigned)f2b(v.y) << 16);
    o.y = (unsigned)f2b(v.z) | ((unsigned)f2b(v.w) << 16);
    ((uint2*)d)[off] = o;
  } else if (blk < 11264) {    // ---- RoPE cos/sin table
    int idx = (blk - 7168) * 256 + t;   // 1048576
    int pos = idx >> 9, i = idx & 511;
    float ifreq = exp2f(-(float)(2 * i) * (13.287712379549449f / 1024.0f));
    float ang = (float)pos * ifreq;
    rtab[idx] = make_float2(__cosf(ang), __sinf(ang));
  } else if (blk < 12288) {    // ---- mask -> bf16*log2e in S^T fragment order
    int mb = blk - 11264;      // 0..1023
    int kt = mb & 31, qt = (mb >> 5) & 15, bb = mb >> 9;
    const float* src = mask + ((size_t)bb * 2048 + qt * 128) * 2048 + kt * 64;
    #pragma unroll
    for (int it = 0; it < 8; it++) {
      int id = it * 256 + t;            // 0..2047 float4 groups (128 x 16)
      int r = id >> 4, c4 = (id & 15) * 4;
      float4 v = *(const float4*)(src + (size_t)r * 2048 + c4);
      T[r * 68 + c4 + 0] = f2b(v.x * LOG2E);
      T[r * 68 + c4 + 1] = f2b(v.y * LOG2E);
      T[r * 68 + c4 + 2] = f2b(v.z * LOG2E);
      T[r * 68 + c4 + 3] = f2b(v.w * LOG2E);
    }
    __syncthreads();
    size_t obase = (size_t)(((bb * 16 + qt) * 32) + kt) * 8192;
    #pragma unroll
    for (int it = 0; it < 2; it++) {
      int pos = it * 256 + t;           // 0..511
      int l15 = pos & 15, g = pos >> 4;
      int w = g >> 3, p = (g >> 2) & 1, qd = g & 3;
      int qlocal = w * 32 + p * 16 + l15;
      u16 vals[16];
      #pragma unroll
      for (int mt = 0; mt < 4; mt++)
        #pragma unroll
        for (int reg = 0; reg < 4; reg++)
          vals[mt * 4 + reg] = T[qlocal * 68 + mt * 16 + qd * 4 + reg];
      uint4* dst = (uint4*)(maskp + obase + (size_t)pos * 16);
      dst[0] = *(uint4*)&vals[0];
      dst[1] = *(uint4*)&vals[8];
    }
  } else {                     // ---- LayerNorm rows 0..4095 -> bf16
    int row = blk - 12288;
    const float* xr = x + (size_t)row * 1024;
    float4 v = *(const float4*)(xr + t * 4);
    float s = v.x + v.y + v.z + v.w;
    float ss = v.x * v.x + v.y * v.y + v.z * v.z + v.w * v.w;
    #pragma unroll
    for (int m = 1; m < 64; m <<= 1) {
      s  += __shfl_xor(s, m);
      ss += __shfl_xor(ss, m);
    }
    int wave = t >> 6, lane = t & 63;
    if (lane == 0) { sbuf[wave] = s; ssbuf[wave] = ss; }
    __syncthreads();
    s  = sbuf[0] + sbuf[1] + sbuf[2] + sbuf[3];
    ss = ssbuf[0] + ssbuf[1] + ssbuf[2] + ssbuf[3];
    float mean = s * (1.0f / 1024.0f);
    float var  = ss * (1.0f / 1024.0f) - mean * mean;
    float rstd = 1.0f / sqrtf(var + 1e-5f);
    float4 gv = *(const float4*)(ln_g + t * 4);
    float4 bv = *(const float4*)(ln_b + t * 4);
    uint2 o;
    o.x = (unsigned)f2b((v.x - mean) * rstd * gv.x + bv.x) |
          ((unsigned)f2b((v.y - mean) * rstd * gv.y + bv.y) << 16);
    o.y = (unsigned)f2b((v.z - mean) * rstd * gv.z + bv.z) |
          ((unsigned)f2b((v.w - mean) * rstd * gv.w + bv.w) << 16);
    *(uint2*)(xn + (size_t)row * 1024 + t * 4) = o;
  }
}

// ======== GEMM: BK=32, 3-buffer distance-2 pipeline, global_load_lds DMA
// staging, counted vmcnt(4) at barriers. Linear [128][32] LDS tiles with chunk
// swizzle (both-sides involution). K=1024 assumed (32 tiles).
// XCD-aware blockIdx swizzle (T1): flat dispatch id is remapped so each XCD
// (id%8) owns a CONTIGUOUS chunk of tiles (consecutive ids share the same
// A-row-panel -> A panels become XCD-L2-local instead of 8x-replicated).
// Bijective: grid sizes 768 and 256 are divisible by 8. Pure index remap —
// identical tiles computed, zero numerical change. ========
template<bool SLAB, bool OUT_BF16, bool ROPE, bool WVT>
__global__ __launch_bounds__(256, 3) void gemm_pipe(const u16* __restrict__ A, int lda,
                                                    const u16* __restrict__ W,
                                                    const float* __restrict__ bias,
                                                    const float2* __restrict__ rtab,
                                                    float* __restrict__ Cf,
                                                    u16* __restrict__ Cb,
                                                    u16* __restrict__ vT,
                                                    int ldc, int K) {
  __shared__ u16 As[3][128 * 32];
  __shared__ u16 Bs[3][128 * 32];
  int nbx = gridDim.x;
  int flat = blockIdx.y * nbx + blockIdx.x;          // HW dispatch order (x fastest)
  int chunk = (nbx * gridDim.y) >> 3;                // nwg divisible by 8
  int sw = (flat & 7) * chunk + (flat >> 3);         // XCD flat&7 gets contiguous run
  int n0 = (sw % nbx) * 128, m0 = (sw / nbx) * 128;
  int aoff = SLAB ? ((n0 >> 10) << 10) : 0;
  int tid = threadIdx.x;
  int lane = tid & 63, l15 = lane & 15, quad = lane >> 4;
  int w = tid >> 6, mw = w & 1, nw = w >> 1;
  const u16* Abase = A + (size_t)m0 * lda + aoff;
  const u16* Wbase = W + (size_t)n0 * K;
  f32x4 acc[4][4];
  #pragma unroll
  for (int i = 0; i < 4; i++)
    #pragma unroll
    for (int j = 0; j < 4; j++) acc[i][j] = (f32x4){0.f, 0.f, 0.f, 0.f};

  // per-lane DMA source pointers (chunk-swizzled); advance +64B per tile
  int rl = lane >> 2;
  int qs = ((lane & 3) ^ ((lane >> 3) & 3)) * 16;   // byte offset of 16B chunk
  const char* gA0 = (const char*)(Abase + (size_t)(w * 16 + rl) * lda) + qs;
  const char* gA1 = (const char*)(Abase + (size_t)((w + 4) * 16 + rl) * lda) + qs;
  const char* gB0 = (const char*)(Wbase + (size_t)(w * 16 + rl) * K) + qs;
  const char* gB1 = (const char*)(Wbase + (size_t)((w + 4) * 16 + rl) * K) + qs;
  int p16 = (quad ^ ((l15 >> 1) & 3)) * 8;          // u16 offset of swizzled chunk

  #define ISSUE(bf)                                                           \
    gload_lds16(gA0, &As[bf][(w) * 512]);                                     \
    gload_lds16(gA1, &As[bf][(w + 4) * 512]);                                 \
    gload_lds16(gB0, &Bs[bf][(w) * 512]);                                     \
    gload_lds16(gB1, &Bs[bf][(w + 4) * 512]);                                 \
    gA0 += 64; gA1 += 64; gB0 += 64; gB1 += 64;
  #define WBAR4() asm volatile("s_waitcnt vmcnt(4) lgkmcnt(0)\n\ts_barrier" ::: "memory")
  #define WBAR0() asm volatile("s_waitcnt vmcnt(0) lgkmcnt(0)\n\ts_barrier" ::: "memory")
  #define COMPUTE(bf)                                                         \
    {                                                                         \
      short8 af[4], bfr[4];                                                   \
      _Pragma("unroll")                                                       \
      for (int mt = 0; mt < 4; mt++)                                          \
        af[mt] = *(const short8*)&As[bf][(mw * 64 + mt * 16 + l15) * 32 + p16]; \
      _Pragma("unroll")                                                       \
      for (int nt = 0; nt < 4; nt++)                                          \
        bfr[nt] = *(const short8*)&Bs[bf][(nw * 64 + nt * 16 + l15) * 32 + p16]; \
      _Pragma("unroll")                                                       \
      for (int mt = 0; mt < 4; mt++)                                          \
        _Pragma("unroll")                                                     \
        for (int nt = 0; nt < 4; nt++)                                        \
          acc[mt][nt] = __builtin_amdgcn_mfma_f32_16x16x32_bf16(              \
              af[mt], bfr[nt], acc[mt][nt], 0, 0, 0);                         \
    }

  ISSUE(0);            // tile 0
  ISSUE(1);            // tile 1
  WBAR4();             // tile 0 resident
  #pragma unroll 1
  for (int tt = 0; tt < 10; ++tt) {
    ISSUE(2); COMPUTE(0); WBAR4();
    ISSUE(0); COMPUTE(1); WBAR4();
    ISSUE(1); COMPUTE(2); WBAR4();
  }
  COMPUTE(0); WBAR0(); // tile 30; drain tile 31
  COMPUTE(1);          // tile 31
  #undef ISSUE
  #undef WBAR4
  #undef WBAR0
  #undef COMPUTE

  int mb = m0 + mw * 64, nb = n0 + nw * 64;
  float bv[4];
  #pragma unroll
  for (int nt = 0; nt < 4; nt++) bv[nt] = bias[nb + nt * 16 + l15];
  #pragma unroll
  for (int mt = 0; mt < 4; mt++)
    #pragma unroll
    for (int nt = 0; nt < 4; nt++) {
      int col = nb + nt * 16 + l15;
      if (WVT && col >= 2048) {
        // v-columns: write transposed to vT[bb][h][d][s] (4 consecutive s per lane)
        int hh = (col - 2048) >> 6, dd = (col - 2048) & 63;
        int row0 = mb + mt * 16 + quad * 4;
        int bbi = row0 >> 11, s0 = row0 & 2047;
        u16 vv[4];
        #pragma unroll
        for (int reg = 0; reg < 4; reg++) vv[reg] = f2b(acc[mt][nt][reg] + bv[nt]);
        *(uint2*)&vT[((size_t)((bbi * 16 + hh) * 64 + dd)) * 2048 + s0] = *(uint2*)vv;
      } else {
        #pragma unroll
        for (int reg = 0; reg < 4; reg++) {
          int row = mb + mt * 16 + quad * 4 + reg;   // C/D: row=quad*4+reg, col=l15
          float val = acc[mt][nt][reg] + bv[nt];
          if (ROPE && col < 2048) {
            float pr = __shfl_xor(val, 1);
            float2 cs = rtab[(size_t)(row & 2047) * 512 + ((col & 1023) >> 1)];
            val = (col & 1) ? fmaf(val, cs.x, pr * cs.y)
                            : fmaf(val, cs.x, -pr * cs.y);
          }
          if (OUT_BF16) Cb[(size_t)row * ldc + col] = f2b(val);
          else          Cf[(size_t)row * ldc + col] = val;
        }
      }
    }
}

// ---------------- Flash attention: MQ=128, 8 waves = 4 q-groups x 2 k-halves ----------------
// Round-2 verified kernel, verbatim (best measured: 56.3us). Wave (wq,wk) computes
// q rows [wq*32,+32) x k cols [wk*32,+32) per tile; P write->read wave-local;
// O partials + row sums combined across k-waves once at the end.
// (Grid already has XCD locality: same-h blocks are stride-16 apart == 0 mod 8.)
__global__ __launch_bounds__(512, 4) void attn_mfma(const u16* __restrict__ qkv2,
                                                    const u16* __restrict__ vT,
                                                    const u16* __restrict__ maskp,
                                                    u16* __restrict__ attn_out) {
  __shared__ u16 Kb[2][64 * 72];
  __shared__ u16 Vb[2][64 * 72];
  __shared__ u16 Ps[128 * 72];
  __shared__ float lsf[128];     // [wq][p][l15] row-sum partials from wk=1 waves
  int h = blockIdx.x, qt = blockIdx.y, bb = blockIdx.z;
  int tid = threadIdx.x;
  int lane = tid & 63, l15 = lane & 15, quad = lane >> 4;
  int w = tid >> 6;
  int wq = w & 3, wk = w >> 2;             // q-group 0..3, k-half 0..1
  int sr = tid >> 3, sc = (tid & 7) * 8;   // K/V staging: 1 uint4 per thread (64x64 tile)
  const u16* kslab = qkv2 + ((size_t)bb * 2048) * 3072 + 1024 + h * 64;
  const u16* vslab = vT + ((size_t)((bb * 16 + h) * 64)) * 2048;

  {  // stage Q rows 0..127 (all waves cooperate; barrier below before bq reads)
    int r = tid >> 2, c0 = (tid & 3) * 16;
    const u16* src = qkv2 + (size_t)(bb * 2048 + qt * 128 + r) * 3072 + h * 64 + c0;
    *(uint4*)&Ps[r * 72 + c0]     = *(const uint4*)src;
    *(uint4*)&Ps[r * 72 + c0 + 8] = *(const uint4*)(src + 8);
  }
  {  // stage K/V tile 0
    *(uint4*)&Kb[0][sr * 72 + sc] = *(const uint4*)(kslab + (size_t)sr * 3072 + sc);
    *(uint4*)&Vb[0][sr * 72 + sc] = *(const uint4*)(vslab + (size_t)sr * 2048 + sc);
  }
  // mask fragment base: u16 idx = ((wq*8 + p*4 + quad)*16 + l15)*16 + wk*8  (p=1: +1024)
  const u16* mbase = maskp + ((size_t)((bb * 16 + qt) * 32)) * 8192
                     + ((wq * 8 + quad) * 16 + l15) * 16 + wk * 8;
  uint4 m0 = *(const uint4*)mbase;
  uint4 m1 = *(const uint4*)(mbase + 1024);

  float lsum[2] = {0.f, 0.f};
  f32x4 acc[2][4];
  #pragma unroll
  for (int p = 0; p < 2; p++)
    #pragma unroll
    for (int dt = 0; dt < 4; dt++) acc[p][dt] = (f32x4){0.f, 0.f, 0.f, 0.f};
  wg_barrier();

  short8 bq[2][2];
  #pragma unroll
  for (int p = 0; p < 2; p++)
    #pragma unroll
    for (int hk = 0; hk < 2; hk++)
      bq[p][hk] = *(const short8*)&Ps[(wq * 32 + p * 16 + l15) * 72 + hk * 32 + quad * 8];

  for (int kt = 0; kt < 32; kt++) {
    int b = kt & 1;
    uint4 kr, vr, m0n, m1n;
    if (kt + 1 < 32) {  // prefetch next K/V tile and next mask fragments
      kr = *(const uint4*)(kslab + (size_t)((kt + 1) * 64 + sr) * 3072 + sc);
      vr = *(const uint4*)(vslab + (size_t)sr * 2048 + (kt + 1) * 64 + sc);
      m0n = *(const uint4*)(mbase + (size_t)(kt + 1) * 8192);
      m1n = *(const uint4*)(mbase + (size_t)(kt + 1) * 8192 + 1024);
    }
    short8 ak[2][2];
    #pragma unroll
    for (int mt = 0; mt < 2; mt++)
      #pragma unroll
      for (int hk = 0; hk < 2; hk++)
        ak[mt][hk] = *(const short8*)&Kb[b][(wk * 32 + mt * 16 + l15) * 72 + hk * 32 + quad * 8];
    f32x4 st[2][2];
    #pragma unroll
    for (int p = 0; p < 2; p++)
      #pragma unroll
      for (int mt = 0; mt < 2; mt++) {
        f32x4 z = (f32x4){0.f, 0.f, 0.f, 0.f};
        z = __builtin_amdgcn_mfma_f32_16x16x32_bf16(ak[mt][0], bq[p][0], z, 0, 0, 0);
        st[p][mt] = __builtin_amdgcn_mfma_f32_16x16x32_bf16(ak[mt][1], bq[p][1], z, 0, 0, 0);
      }
    #pragma unroll
    for (int p = 0; p < 2; p++) {
      uint4 mm = p ? m1 : m0;
      u32 wds[4] = {mm.x, mm.y, mm.z, mm.w};
      float mv[8];
      #pragma unroll
      for (int j = 0; j < 4; j++) {
        mv[2 * j]     = __uint_as_float(wds[j] << 16);
        mv[2 * j + 1] = __uint_as_float(wds[j] & 0xffff0000u);
      }
      int prow = (wq * 32 + p * 16 + l15) * 72 + wk * 32 + quad * 4;
      #pragma unroll
      for (int mt = 0; mt < 2; mt++) {
        float sv0 = fmaf(st[p][mt][0], SCALE2, mv[mt * 4 + 0]);
        float sv1 = fmaf(st[p][mt][1], SCALE2, mv[mt * 4 + 1]);
        float sv2 = fmaf(st[p][mt][2], SCALE2, mv[mt * 4 + 2]);
        float sv3 = fmaf(st[p][mt][3], SCALE2, mv[mt * 4 + 3]);
        float p0 = __builtin_amdgcn_exp2f(sv0), p1 = __builtin_amdgcn_exp2f(sv1);
        float p2 = __builtin_amdgcn_exp2f(sv2), p3 = __builtin_amdgcn_exp2f(sv3);
        lsum[p] += (p0 + p1) + (p2 + p3);
        u32 pk0, pk1;
        asm("v_cvt_pk_bf16_f32 %0, %1, %2" : "=v"(pk0) : "v"(p0), "v"(p1));
        asm("v_cvt_pk_bf16_f32 %0, %1, %2" : "=v"(pk1) : "v"(p2), "v"(p3));
        *(uint2*)&Ps[prow + mt * 16] = make_uint2(pk0, pk1);
      }
    }
    short8 ap[2];
    #pragma unroll
    for (int p = 0; p < 2; p++)
      ap[p] = *(const short8*)&Ps[(wq * 32 + p * 16 + l15) * 72 + wk * 32 + quad * 8];
    #pragma unroll
    for (int dt = 0; dt < 4; dt++) {
      short8 bv = *(const short8*)&Vb[b][(dt * 16 + l15) * 72 + wk * 32 + quad * 8];
      #pragma unroll
      for (int p = 0; p < 2; p++)
        acc[p][dt] = __builtin_amdgcn_mfma_f32_16x16x32_bf16(ap[p], bv, acc[p][dt], 0, 0, 0);
    }
    if (kt + 1 < 32) {
      int nb = b ^ 1;
      *(uint4*)&Kb[nb][sr * 72 + sc] = kr;
      *(uint4*)&Vb[nb][sr * 72 + sc] = vr;
      m0 = m0n; m1 = m1n;
    }
    wg_barrier();
  }

  // ---- cross-k-wave combine: wk=1 dumps O-partials + row sums; wk=0 merges ----
  float* fs = ((wq < 2) ? (float*)&Kb[0][0] : (float*)&Vb[0][0]) + (wq & 1) * 2176;
  if (wk) {
    #pragma unroll
    for (int p = 0; p < 2; p++) {
      #pragma unroll
      for (int dt = 0; dt < 4; dt++)
        #pragma unroll
        for (int reg = 0; reg < 4; reg++)
          fs[(p * 16 + quad * 4 + reg) * 68 + dt * 16 + l15] = acc[p][dt][reg];
      float l = lsum[p];
      l += __shfl_xor(l, 16);
      l += __shfl_xor(l, 32);
      if (lane < 16) lsf[(wq * 2 + p) * 16 + l15] = l;
    }
  }
  wg_barrier();
  if (!wk) {
    #pragma unroll
    for (int p = 0; p < 2; p++) {
      float l = lsum[p];
      l += __shfl_xor(l, 16);
      l += __shfl_xor(l, 32);
      l += lsf[(wq * 2 + p) * 16 + l15];     // full row sum for q = l15 (local)
      #pragma unroll
      for (int reg = 0; reg < 4; reg++) {
        float lq = __shfl(l, quad * 4 + reg);
        float inv = 1.0f / lq;
        int grow = bb * 2048 + qt * 128 + wq * 32 + p * 16 + quad * 4 + reg;
        #pragma unroll
        for (int dt = 0; dt < 4; dt++) {
          float o = acc[p][dt][reg] + fs[(p * 16 + quad * 4 + reg) * 68 + dt * 16 + l15];
          attn_out[(size_t)grow * 1024 + h * 64 + dt * 16 + l15] = f2b(o * inv);
        }
      }
    }
  }
}

extern "C" void kernel_launch(void* const* d_in, const int* in_sizes, int n_in,
                              void* d_out, int out_size, void* d_ws, size_t ws_size,
                              hipStream_t stream) {
  const float* x     = (const float*)d_in[0];
  const float* mask  = (const float*)d_in[1];
  const float* ln_g  = (const float*)d_in[2];
  const float* ln_b  = (const float*)d_in[3];
  const float* w_qkv = (const float*)d_in[4];
  const float* b_qkv = (const float*)d_in[5];
  const float* in_w  = (const float*)d_in[6];
  const float* in_b  = (const float*)d_in[7];
  const float* out_w = (const float*)d_in[8];
  const float* out_b = (const float*)d_in[9];
  float* out = (float*)d_out;
  char* ws = (char*)d_ws;

  u16* wqkv_b = (u16*)(ws);                   //  6291456  (3072x1024)
  u16* inw_b  = (u16*)(ws + 6291456ull);      //  6291456  (3072x1024)
  u16* outw_b = (u16*)(ws + 12582912ull);     //  2097152  (1024x1024)
  u16* xn_b   = (u16*)(ws + 14680064ull);     //  8388608  (4096x1024)
  u16* attn_b = xn_b;                         //  reuse (xn dead after gemm1)
  u16* qkv_b  = (u16*)(ws + 23068672ull);     // 25165824  (4096x3072)
  u16* qkv2_b = (u16*)(ws + 48234496ull);     // 25165824  (4096x3072; v cols unused)
  float2* rtab = (float2*)qkv2_b;             //  8388608  aliases qkv2 (dead before gemm2)
  u16* vT     = (u16*)(ws + 73400320ull);     //  8388608  (2,16,64,2048)
  u16* maskp  = (u16*)(ws + 81788928ull);     // 16777216  (2*16*32 tiles * 8192 u16)

  prep<<<16384, 256, 0, stream>>>(w_qkv, wqkv_b, in_w, inw_b, out_w, outw_b,
                                  rtab, mask, maskp, x, ln_g, ln_b, xn_b);
  gemm_pipe<false, true, true, false><<<dim3(24, 32), 256, 0, stream>>>(
      xn_b, 1024, wqkv_b, b_qkv, rtab, nullptr, qkv_b, nullptr, 3072, 1024);
  gemm_pipe<true, true, false, true><<<dim3(24, 32), 256, 0, stream>>>(
      qkv_b, 3072, inw_b, in_b, nullptr, nullptr, qkv2_b, vT, 3072, 1024);
  attn_mfma<<<dim3(16, 16, 2), 512, 0, stream>>>(qkv2_b, vT, maskp, attn_b);
  gemm_pipe<false, false, false, false><<<dim3(8, 32), 256, 0, stream>>>(
      attn_b, 1024, outw_b, out_b, nullptr, out, nullptr, nullptr, 1024, 1024);
}